// Round 12
// baseline (512.414 us; speedup 1.0000x reference)
//
#include <hip/hip_runtime.h>

typedef _Float16 half_t;
typedef _Float16 f16x8 __attribute__((ext_vector_type(8)));
typedef _Float16 f16x4 __attribute__((ext_vector_type(4)));
typedef float f32x4 __attribute__((ext_vector_type(4)));
typedef unsigned long long u64;

#define NN 6144
#define IN_DIM 512
#define DD 256
#define OUT_DIM 128
#define SPLIT 4
#define JT 24        // j-tiles of 64 per slice (1536/64)
#define LOG2E 1.44269504088896340736f

__device__ __forceinline__ f32x4 mfma16(f16x8 a, f16x8 b, f32x4 c) {
  return __builtin_amdgcn_mfma_f32_16x16x32_f16(a, b, c, 0, 0, 0);
}

// LDS-only barrier (P visibility); vmcnt intentionally NOT drained.
#define LBAR() asm volatile("s_waitcnt lgkmcnt(0)\n\ts_barrier" ::: "memory")
// counted vmem wait: drains down to N outstanding vmem ops.
#define VWAIT(N) asm volatile("s_waitcnt vmcnt(" #N ")" ::: "memory")

// ---------------- convert x (f32 -> f16) ----------------
__global__ void cvt_x_kernel(const float* __restrict__ x, half_t* __restrict__ xh) {
  int idx = (blockIdx.x * 256 + threadIdx.x) * 4;
  float4 v = *(const float4*)(x + idx);
  f16x4 h;
  h[0] = (half_t)v.x; h[1] = (half_t)v.y; h[2] = (half_t)v.z; h[3] = (half_t)v.w;
  *(f16x4*)(xh + idx) = h;
}

// ---------------- convert + transpose weights ----------------
__global__ void cvt_w_kernel(const float* __restrict__ W0, const float* __restrict__ W1,
                             const float* __restrict__ W2, const float* __restrict__ pW,
                             half_t* __restrict__ WT, half_t* __restrict__ pWT) {
  int y = blockIdx.y;
  int idx = blockIdx.x * 256 + threadIdx.x;
  if (y < 3) {
    const float* W = (y == 0) ? W0 : (y == 1) ? W1 : W2;
    int k = idx >> 8, n = idx & 255;
    WT[(size_t)y * DD * IN_DIM + (size_t)n * IN_DIM + k] = (half_t)W[idx];
  } else if (idx < DD * OUT_DIM) {
    int k = idx >> 7, o = idx & 127;
    pWT[(size_t)o * DD + k] = (half_t)pW[idx];
  }
}

// ---------------- GEMM1 + fused e-scores ----------------
__global__ __launch_bounds__(256, 2) void gemm1_kernel(
    const half_t* __restrict__ xh, const half_t* __restrict__ WT,
    const float* __restrict__ as0, const float* __restrict__ as1, const float* __restrict__ as2,
    const float* __restrict__ ad0, const float* __restrict__ ad1, const float* __restrict__ ad2,
    half_t* __restrict__ hT, float* __restrict__ e1, float* __restrict__ e2) {
  int v = blockIdx.y;
  int i0 = blockIdx.x * 64;
  int t = threadIdx.x;
  int lane = t & 63, w = t >> 6;
  int lr = lane & 15, lg = lane >> 4;
  const half_t* Wv = WT + (size_t)v * DD * IN_DIM;
  const float* asv = (v == 0) ? as0 : (v == 1) ? as1 : as2;
  const float* adv = (v == 0) ? ad0 : (v == 1) ? ad1 : ad2;
  f32x4 acc[4][4] = {};
  for (int kt = 0; kt < 16; ++kt) {
    int k = kt * 32 + lg * 8;
    f16x8 af[4], bf[4];
#pragma unroll
    for (int mf = 0; mf < 4; ++mf)
      af[mf] = *(const f16x8*)(xh + (size_t)(i0 + mf * 16 + lr) * IN_DIM + k);
#pragma unroll
    for (int nf = 0; nf < 4; ++nf)
      bf[nf] = *(const f16x8*)(Wv + (size_t)(w * 64 + nf * 16 + lr) * IN_DIM + k);
#pragma unroll
    for (int mf = 0; mf < 4; ++mf)
#pragma unroll
      for (int nf = 0; nf < 4; ++nf)
        acc[mf][nf] = mfma16(af[mf], bf[nf], acc[mf][nf]);
  }
  __shared__ half_t tr[4][64 * 64];
  __shared__ float ep1[4][64], ep2[4][64];
  char* trw = (char*)tr[w];
#pragma unroll
  for (int mf = 0; mf < 4; ++mf)
#pragma unroll
    for (int nf = 0; nf < 4; ++nf)
#pragma unroll
      for (int r = 0; r < 4; ++r) {
        int dl = nf * 16 + lr;
        int il = mf * 16 + lg * 4 + r;
        unsigned addr = (unsigned)((dl * 128 + il * 2) ^ ((dl & 7) << 4));
        *(half_t*)(trw + addr) = (half_t)acc[mf][nf][r];
      }
  float as_c[4], ad_c[4];
#pragma unroll
  for (int nf = 0; nf < 4; ++nf) {
    int col = w * 64 + nf * 16 + lr;
    as_c[nf] = asv[col];
    ad_c[nf] = adv[col];
  }
#pragma unroll
  for (int mf = 0; mf < 4; ++mf)
#pragma unroll
    for (int r = 0; r < 4; ++r) {
      float p1 = 0.f, p2 = 0.f;
#pragma unroll
      for (int nf = 0; nf < 4; ++nf) {
        p1 = fmaf(acc[mf][nf][r], as_c[nf], p1);
        p2 = fmaf(acc[mf][nf][r], ad_c[nf], p2);
      }
      p1 += __shfl_xor(p1, 1); p1 += __shfl_xor(p1, 2);
      p1 += __shfl_xor(p1, 4); p1 += __shfl_xor(p1, 8);
      p2 += __shfl_xor(p2, 1); p2 += __shfl_xor(p2, 2);
      p2 += __shfl_xor(p2, 4); p2 += __shfl_xor(p2, 8);
      if (lr == 0) {
        int il = mf * 16 + lg * 4 + r;
        ep1[w][il] = p1;
        ep2[w][il] = p2;
      }
    }
  __syncthreads();
  half_t* hTv = hT + (size_t)v * DD * NN;
#pragma unroll
  for (int c = 0; c < 8; ++c) {
    unsigned addr = (unsigned)((lane * 128 + c * 16) ^ ((lane & 7) << 4));
    f16x8 val = *(const f16x8*)(trw + addr);
    *(f16x8*)(hTv + (size_t)(w * 64 + lane) * NN + i0 + c * 8) = val;
  }
  if (t < 64) {
    e1[v * NN + i0 + t] = LOG2E * (ep1[0][t] + ep1[1][t] + ep1[2][t] + ep1[3][t]);
    e2[v * NN + i0 + t] = LOG2E * (ep2[0][t] + ep2[1][t] + ep2[2][t] + ep2[3][t]);
  }
}

// ---------------- e2 max per view ----------------
__global__ void e2max_kernel(const float* __restrict__ e2, float* __restrict__ e2m) {
  int v = blockIdx.x;
  __shared__ float red[256];
  float m = -1e30f;
  for (int i = threadIdx.x; i < NN; i += 256) m = fmaxf(m, e2[v * NN + i]);
  red[threadIdx.x] = m;
  __syncthreads();
  for (int s = 128; s > 0; s >>= 1) {
    if (threadIdx.x < s) red[threadIdx.x] = fmaxf(red[threadIdx.x], red[threadIdx.x + s]);
    __syncthreads();
  }
  if (threadIdx.x == 0) e2m[v] = red[0];
}

// ---------------- fused GAT aggregation: 8-wave, counted-vmcnt pipeline ----------------
// grid (96, SPLIT, 3), 512 threads (8 waves), 2 blocks/CU. Wave w: 64 rows x
// d in [w*32, w*32+32). Per region t:
//   comp_p(t) -> lgkm-barrier -> issue gload(t+1), adj(t+2), e2(t+2)
//   -> vmcnt(10) (drains exactly gload(t)) -> mfma(t).
// adj prefetch depth = 2 regions (~HBM latency); gload depth = 1.
// Steady-state vmem/region = 4 gload + 2 adj + 1 e2 = 7.
__global__ __launch_bounds__(512, 4) void gat_kernel(
    const int* __restrict__ adj0, const int* __restrict__ adj1, const int* __restrict__ adj2,
    const half_t* __restrict__ hT,
    const float* __restrict__ e1g, const float* __restrict__ e2g,
    const float* __restrict__ e2maxg, half_t* __restrict__ pacc, float* __restrict__ pl) {
  int v = blockIdx.z, s = blockIdx.y;
  const int* __restrict__ adjv = (v == 0) ? adj0 : (v == 1) ? adj1 : adj2;
  int i0 = blockIdx.x * 64;
  int t = threadIdx.x;
  int lane = t & 63, w = t >> 6;       // 8 waves
  int lr = lane & 15, lg = lane >> 4;
  int jq = t & 15, rg = t >> 4;        // rg 0..31: thread covers rows rg, rg+32

  __shared__ half_t H0[DD * 64];       // 32 KB
  __shared__ half_t H1[DD * 64];       // 32 KB
  __shared__ half_t P0[64 * 64];       // 8 KB
  __shared__ half_t P1[64 * 64];       // 8 KB

  const half_t* hTv = hT + (size_t)v * DD * NN;
  const float* e2v = e2g + v * NN;
  const int jbase = s * JT * 64;

  float e1r[2], mr[2];
  float e2mL = e2maxg[v];
#pragma unroll
  for (int it = 0; it < 2; ++it) {
    float e1i = e1g[v * NN + i0 + it * 32 + rg];
    e1r[it] = e1i;
    float sm = e1i + e2mL;
    mr[it] = fmaxf(sm, 0.2f * sm);     // lrelu upper bound of row max (log2 units)
  }

  f32x4 acc[4][2] = {};
  float lpart[2] = {0.f, 0.f};

  // coalesced hT staging (r6-verified pre-swizzle); wave w stages d [w*32,w*32+32)
  int sub = lane >> 3;
  int c_src = (lane & 7) ^ sub;
  auto gload = [&](half_t* hb, int jt) {
    int j0 = jbase + jt * 64;
#pragma unroll
    for (int q = 0; q < 4; ++q) {
      const half_t* gp = hTv + (size_t)(w * 32 + q * 8 + sub) * NN + j0 + c_src * 8;
      half_t* lp = hb + (w * 32 + q * 8) * 64;
      __builtin_amdgcn_global_load_lds(
          (const __attribute__((address_space(1))) int*)gp,
          (__attribute__((address_space(3))) int*)lp, 16, 0, 0);
    }
  };
  auto load_adj = [&](int4 (&aw)[2], int jt) {
    int j0 = jbase + jt * 64;
    aw[0] = *(const int4*)(adjv + (size_t)(i0 + rg) * NN + j0 + jq * 4);
    aw[1] = *(const int4*)(adjv + (size_t)(i0 + 32 + rg) * NN + j0 + jq * 4);
  };
  auto comp_p = [&](const int4 (&aw)[2], const float4& e2q, char* pb) {
    float e2a[4] = {e2q.x, e2q.y, e2q.z, e2q.w};
#pragma unroll
    for (int it = 0; it < 2; ++it) {
      int il = it * 32 + rg;
      int a4[4] = {aw[it].x, aw[it].y, aw[it].z, aw[it].w};
      f16x4 ph;
      float ssum = 0.f;
#pragma unroll
      for (int c = 0; c < 4; ++c) {
        float s1 = e1r[it] + e2a[c];
        float u = fmaxf(s1, 0.2f * s1) - mr[it];
        float p = (a4[c] > 0) ? exp2f(u) : 0.f;
        ssum += p;
        ph[c] = (half_t)p;
      }
      lpart[it] += ssum;
      unsigned addr = (unsigned)((il * 128 + jq * 8) ^ ((il & 7) << 4));
      *(f16x4*)(pb + addr) = ph;
    }
  };
  auto do_mfma = [&](const char* pb, const half_t* hb) {
#pragma unroll
    for (int kf = 0; kf < 2; ++kf) {
      f16x8 bfr[2];
#pragma unroll
      for (int nf = 0; nf < 2; ++nf) {
        int d = w * 32 + nf * 16 + lr;
        unsigned ba = (unsigned)(d * 128 + ((kf * 64 + lg * 16) ^ ((lr & 7) << 4)));
        bfr[nf] = *(const f16x8*)((const char*)hb + ba);
      }
#pragma unroll
      for (int mf = 0; mf < 4; ++mf) {
        int row = mf * 16 + lr;
        unsigned pa_ = (unsigned)((row * 128 + kf * 64 + lg * 16) ^ ((row & 7) << 4));
        f16x8 af = *(const f16x8*)(pb + pa_);
#pragma unroll
        for (int nf = 0; nf < 2; ++nf)
          acc[mf][nf] = mfma16(af, bfr[nf], acc[mf][nf]);
      }
    }
  };

  int4 awA[2], awB[2], awC[2];
  float4 e2A, e2B, e2C;

  // prologue: gload(0) FIRST (oldest vmem), then adj/e2 for tiles 0,1
  gload(H0, 0);
  load_adj(awA, 0);
  e2A = *(const float4*)(e2v + jbase + jq * 4);
  load_adj(awB, 1);
  e2B = *(const float4*)(e2v + jbase + 64 + jq * 4);

#define REGION(T, AWc, AWn, E2c, E2n, Pc, Hc, Hn, VN)                \
  {                                                                  \
    comp_p(AWc, E2c, (char*)(Pc));                                   \
    LBAR();                                                          \
    if ((T) + 1 < JT) gload(Hn, (T) + 1);                            \
    if ((T) + 2 < JT) {                                              \
      load_adj(AWn, (T) + 2);                                        \
      E2n = *(const float4*)(e2v + jbase + ((T) + 2) * 64 + jq * 4); \
    }                                                                \
    __builtin_amdgcn_sched_barrier(0);                               \
    VWAIT(VN);                                                       \
    __builtin_amdgcn_sched_barrier(0);                               \
    do_mfma((char*)(Pc), Hc);                                        \
  }

  for (int k = 0; k < 18; k += 6) {
    REGION(k + 0, awA, awC, e2A, e2C, P0, H0, H1, 10);
    REGION(k + 1, awB, awA, e2B, e2A, P1, H1, H0, 10);
    REGION(k + 2, awC, awB, e2C, e2B, P0, H0, H1, 10);
    REGION(k + 3, awA, awC, e2A, e2C, P1, H1, H0, 10);
    REGION(k + 4, awB, awA, e2B, e2A, P0, H0, H1, 10);
    REGION(k + 5, awC, awB, e2C, e2B, P1, H1, H0, 10);
  }
  REGION(18, awA, awC, e2A, e2C, P0, H0, H1, 10);
  REGION(19, awB, awA, e2B, e2A, P1, H1, H0, 10);
  REGION(20, awC, awB, e2C, e2B, P0, H0, H1, 10);
  REGION(21, awA, awC, e2A, e2C, P1, H1, H0, 10);
  REGION(22, awB, awA, e2B, e2A, P0, H0, H1, 7);
  REGION(23, awC, awB, e2C, e2B, P1, H1, H0, 0);
#undef REGION

  // row sums: reduce over jq (16-lane groups), thread covers rows rg, rg+32
  size_t sl = (size_t)v * SPLIT + s;
#pragma unroll
  for (int it = 0; it < 2; ++it) {
    float ssum = lpart[it];
    ssum += __shfl_xor(ssum, 1); ssum += __shfl_xor(ssum, 2);
    ssum += __shfl_xor(ssum, 4); ssum += __shfl_xor(ssum, 8);
    if (jq == 0) pl[sl * NN + i0 + it * 32 + rg] = ssum;
  }

  half_t* pa = pacc + sl * (size_t)NN * DD;
#pragma unroll
  for (int mf = 0; mf < 4; ++mf)
#pragma unroll
    for (int r = 0; r < 4; ++r) {
      int il = mf * 16 + lg * 4 + r;
#pragma unroll
      for (int nf = 0; nf < 2; ++nf)
        pa[(size_t)(i0 + il) * DD + w * 32 + nf * 16 + lr] = (half_t)acc[mf][nf][r];
    }
}

// ---------------- proj + LN + weighted combine (fused slice-combine) ----------------
__global__ __launch_bounds__(64) void proj_kernel(
    const half_t* __restrict__ pacc, const float* __restrict__ pl,
    const half_t* __restrict__ pWT,
    const float* __restrict__ proj_b, const float* __restrict__ ln_g,
    const float* __restrict__ ln_b, const float* __restrict__ alpha,
    float* __restrict__ out) {
  int i0 = blockIdx.x * 16;
  int t = threadIdx.x;
  int lr = t & 15, lg = t >> 4;
  float a0 = alpha[0], a1 = alpha[1], a2 = alpha[2];
  float am = fmaxf(a0, fmaxf(a1, a2));
  float x0 = __expf(a0 - am), x1 = __expf(a1 - am), x2 = __expf(a2 - am);
  float inv = 1.f / (x0 + x1 + x2);
  float wv[3] = {x0 * inv, x1 * inv, x2 * inv};
  __shared__ float rlv[3][16];
  if (t < 48) {
    int v = t >> 4, i = t & 15;
    float l = 0.f;
#pragma unroll
    for (int s = 0; s < SPLIT; ++s)
      l += pl[((size_t)v * SPLIT + s) * NN + i0 + i];
    rlv[v][i] = (l > 0.f) ? 1.f / l : 0.f;
  }
  float pb[8], gg[8], bb[8];
#pragma unroll
  for (int nf = 0; nf < 8; ++nf) {
    pb[nf] = proj_b[nf * 16 + lr];
    gg[nf] = ln_g[nf * 16 + lr];
    bb[nf] = ln_b[nf * 16 + lr];
  }
  __syncthreads();
  f32x4 zacc[8] = {};
  for (int v = 0; v < 3; ++v) {
    float rl = rlv[v][lr];
    f32x4 yac[8] = {};
    const half_t* p0 = pacc + (((size_t)v * SPLIT + 0) * NN + i0 + lr) * DD;
    const half_t* p1 = pacc + (((size_t)v * SPLIT + 1) * NN + i0 + lr) * DD;
    const half_t* p2 = pacc + (((size_t)v * SPLIT + 2) * NN + i0 + lr) * DD;
    const half_t* p3 = pacc + (((size_t)v * SPLIT + 3) * NN + i0 + lr) * DD;
    for (int kt = 0; kt < 8; ++kt) {
      int k = kt * 32 + lg * 8;
      f16x8 s0 = *(const f16x8*)(p0 + k);
      f16x8 s1 = *(const f16x8*)(p1 + k);
      f16x8 s2 = *(const f16x8*)(p2 + k);
      f16x8 s3 = *(const f16x8*)(p3 + k);
      f16x8 af;
#pragma unroll
      for (int e = 0; e < 8; ++e)
        af[e] = (half_t)((((float)s0[e] + (float)s1[e]) +
                          ((float)s2[e] + (float)s3[e])) * rl);
#pragma unroll
      for (int nf = 0; nf < 8; ++nf) {
        f16x8 bf = *(const f16x8*)(pWT + (size_t)(nf * 16 + lr) * DD + k);
        yac[nf] = mfma16(af, bf, yac[nf]);
      }
    }
#pragma unroll
    for (int r = 0; r < 4; ++r) {
      float ssum = 0.f, q = 0.f;
#pragma unroll
      for (int nf = 0; nf < 8; ++nf) {
        float y = yac[nf][r] + pb[nf];
        yac[nf][r] = y;
        ssum += y; q += y * y;
      }
      ssum += __shfl_xor(ssum, 1); ssum += __shfl_xor(ssum, 2);
      ssum += __shfl_xor(ssum, 4); ssum += __shfl_xor(ssum, 8);
      q += __shfl_xor(q, 1); q += __shfl_xor(q, 2);
      q += __shfl_xor(q, 4); q += __shfl_xor(q, 8);
      float mean = ssum * (1.f / 128.f);
      float var = q * (1.f / 128.f) - mean * mean;
      float rstd = rsqrtf(var + 1e-5f);
      float wvv = wv[v];
#pragma unroll
      for (int nf = 0; nf < 8; ++nf)
        zacc[nf][r] += wvv * (yac[nf][r] - mean) * rstd;
    }
  }
#pragma unroll
  for (int nf = 0; nf < 8; ++nf)
#pragma unroll
    for (int r = 0; r < 4; ++r) {
      int row = i0 + lg * 4 + r;
      float z = zacc[nf][r] * gg[nf] + bb[nf];
      if (!isfinite(z)) z = 0.f;
      out[(size_t)row * OUT_DIM + nf * 16 + lr] = z;
    }
  if (blockIdx.x == 0 && t < 3) out[(size_t)NN * OUT_DIM + t] = wv[t];
}

// ---------------- launch ----------------
extern "C" void kernel_launch(void* const* d_in, const int* in_sizes, int n_in,
                              void* d_out, int out_size, void* d_ws, size_t ws_size,
                              hipStream_t stream) {
  const float* x      = (const float*)d_in[0];
  const int*   adj_cf = (const int*)d_in[1];
  const int*   adj_or = (const int*)d_in[2];
  const int*   adj_pe = (const int*)d_in[3];
  const float* W_cf   = (const float*)d_in[4];
  const float* as_cf  = (const float*)d_in[5];
  const float* ad_cf  = (const float*)d_in[6];
  const float* W_or   = (const float*)d_in[7];
  const float* as_or  = (const float*)d_in[8];
  const float* ad_or  = (const float*)d_in[9];
  const float* W_pe   = (const float*)d_in[10];
  const float* as_pe  = (const float*)d_in[11];
  const float* ad_pe  = (const float*)d_in[12];
  const float* proj_W = (const float*)d_in[13];
  const float* proj_b = (const float*)d_in[14];
  const float* ln_g   = (const float*)d_in[15];
  const float* ln_b   = (const float*)d_in[16];
  const float* alpha  = (const float*)d_in[17];

  char* ws = (char*)d_ws;
  half_t* xh     = (half_t*)(ws + 0);         // 6291456
  half_t* WT     = (half_t*)(ws + 6291456);   // 786432
  half_t* pWT    = (half_t*)(ws + 7077888);   // 65536
  half_t* hT     = (half_t*)(ws + 7143424);   // 9437184
  float*  e1     = (float*)(ws + 16580608);   // 73728
  float*  e2     = (float*)(ws + 16654336);   // 73728
  float*  e2m    = (float*)(ws + 16728064);   // 64
  half_t* pacc   = (half_t*)(ws + 16728128);  // 3*4*6144*256*2 = 37748736
  float*  pl     = (float*)(ws + 54476864);   // 3*4*6144*4 = 294912 (end ~54.8 MB)

  cvt_x_kernel<<<3072, 256, 0, stream>>>(x, xh);
  cvt_w_kernel<<<dim3(512, 4), 256, 0, stream>>>(W_cf, W_or, W_pe, proj_W, WT, pWT);
  gemm1_kernel<<<dim3(96, 3), 256, 0, stream>>>(xh, WT, as_cf, as_or, as_pe,
                                                ad_cf, ad_or, ad_pe, hT, e1, e2);
  e2max_kernel<<<3, 256, 0, stream>>>(e2, e2m);
  gat_kernel<<<dim3(96, SPLIT, 3), 512, 0, stream>>>(adj_cf, adj_or, adj_pe, hT,
                                                     e1, e2, e2m, pacc, pl);
  proj_kernel<<<384, 64, 0, stream>>>(pacc, pl, pWT, proj_b, ln_g, ln_b, alpha,
                                      (float*)d_out);
}

// Round 13
// 346.481 us; speedup vs baseline: 1.4789x; 1.4789x over previous
//
#include <hip/hip_runtime.h>

typedef _Float16 half_t;
typedef _Float16 f16x8 __attribute__((ext_vector_type(8)));
typedef _Float16 f16x4 __attribute__((ext_vector_type(4)));
typedef float f32x4 __attribute__((ext_vector_type(4)));
typedef unsigned long long u64;

#define NN 6144
#define IN_DIM 512
#define DD 256
#define OUT_DIM 128
#define SPLIT 2
#define JT 48        // j-tiles of 64 per slice (3072/64)
#define LOG2E 1.44269504088896340736f

__device__ __forceinline__ f32x4 mfma16(f16x8 a, f16x8 b, f32x4 c) {
  return __builtin_amdgcn_mfma_f32_16x16x32_f16(a, b, c, 0, 0, 0);
}

// ---------------- convert x (f32 -> f16) ----------------
__global__ void cvt_x_kernel(const float* __restrict__ x, half_t* __restrict__ xh) {
  int idx = (blockIdx.x * 256 + threadIdx.x) * 4;
  float4 v = *(const float4*)(x + idx);
  f16x4 h;
  h[0] = (half_t)v.x; h[1] = (half_t)v.y; h[2] = (half_t)v.z; h[3] = (half_t)v.w;
  *(f16x4*)(xh + idx) = h;
}

// ---------------- convert + transpose weights ----------------
__global__ void cvt_w_kernel(const float* __restrict__ W0, const float* __restrict__ W1,
                             const float* __restrict__ W2, const float* __restrict__ pW,
                             half_t* __restrict__ WT, half_t* __restrict__ pWT) {
  int y = blockIdx.y;
  int idx = blockIdx.x * 256 + threadIdx.x;
  if (y < 3) {
    const float* W = (y == 0) ? W0 : (y == 1) ? W1 : W2;
    int k = idx >> 8, n = idx & 255;
    WT[(size_t)y * DD * IN_DIM + (size_t)n * IN_DIM + k] = (half_t)W[idx];
  } else if (idx < DD * OUT_DIM) {
    int k = idx >> 7, o = idx & 127;
    pWT[(size_t)o * DD + k] = (half_t)pW[idx];
  }
}

// ---------------- GEMM1 + fused e-scores ----------------
__global__ __launch_bounds__(256, 2) void gemm1_kernel(
    const half_t* __restrict__ xh, const half_t* __restrict__ WT,
    const float* __restrict__ as0, const float* __restrict__ as1, const float* __restrict__ as2,
    const float* __restrict__ ad0, const float* __restrict__ ad1, const float* __restrict__ ad2,
    half_t* __restrict__ hT, float* __restrict__ e1, float* __restrict__ e2) {
  int v = blockIdx.y;
  int i0 = blockIdx.x * 64;
  int t = threadIdx.x;
  int lane = t & 63, w = t >> 6;
  int lr = lane & 15, lg = lane >> 4;
  const half_t* Wv = WT + (size_t)v * DD * IN_DIM;
  const float* asv = (v == 0) ? as0 : (v == 1) ? as1 : as2;
  const float* adv = (v == 0) ? ad0 : (v == 1) ? ad1 : ad2;
  f32x4 acc[4][4] = {};
  for (int kt = 0; kt < 16; ++kt) {
    int k = kt * 32 + lg * 8;
    f16x8 af[4], bf[4];
#pragma unroll
    for (int mf = 0; mf < 4; ++mf)
      af[mf] = *(const f16x8*)(xh + (size_t)(i0 + mf * 16 + lr) * IN_DIM + k);
#pragma unroll
    for (int nf = 0; nf < 4; ++nf)
      bf[nf] = *(const f16x8*)(Wv + (size_t)(w * 64 + nf * 16 + lr) * IN_DIM + k);
#pragma unroll
    for (int mf = 0; mf < 4; ++mf)
#pragma unroll
      for (int nf = 0; nf < 4; ++nf)
        acc[mf][nf] = mfma16(af[mf], bf[nf], acc[mf][nf]);
  }
  __shared__ half_t tr[4][64 * 64];
  __shared__ float ep1[4][64], ep2[4][64];
  char* trw = (char*)tr[w];
#pragma unroll
  for (int mf = 0; mf < 4; ++mf)
#pragma unroll
    for (int nf = 0; nf < 4; ++nf)
#pragma unroll
      for (int r = 0; r < 4; ++r) {
        int dl = nf * 16 + lr;
        int il = mf * 16 + lg * 4 + r;
        unsigned addr = (unsigned)((dl * 128 + il * 2) ^ ((dl & 7) << 4));
        *(half_t*)(trw + addr) = (half_t)acc[mf][nf][r];
      }
  float as_c[4], ad_c[4];
#pragma unroll
  for (int nf = 0; nf < 4; ++nf) {
    int col = w * 64 + nf * 16 + lr;
    as_c[nf] = asv[col];
    ad_c[nf] = adv[col];
  }
#pragma unroll
  for (int mf = 0; mf < 4; ++mf)
#pragma unroll
    for (int r = 0; r < 4; ++r) {
      float p1 = 0.f, p2 = 0.f;
#pragma unroll
      for (int nf = 0; nf < 4; ++nf) {
        p1 = fmaf(acc[mf][nf][r], as_c[nf], p1);
        p2 = fmaf(acc[mf][nf][r], ad_c[nf], p2);
      }
      p1 += __shfl_xor(p1, 1); p1 += __shfl_xor(p1, 2);
      p1 += __shfl_xor(p1, 4); p1 += __shfl_xor(p1, 8);
      p2 += __shfl_xor(p2, 1); p2 += __shfl_xor(p2, 2);
      p2 += __shfl_xor(p2, 4); p2 += __shfl_xor(p2, 8);
      if (lr == 0) {
        int il = mf * 16 + lg * 4 + r;
        ep1[w][il] = p1;
        ep2[w][il] = p2;
      }
    }
  __syncthreads();
  half_t* hTv = hT + (size_t)v * DD * NN;
#pragma unroll
  for (int c = 0; c < 8; ++c) {
    unsigned addr = (unsigned)((lane * 128 + c * 16) ^ ((lane & 7) << 4));
    f16x8 val = *(const f16x8*)(trw + addr);
    *(f16x8*)(hTv + (size_t)(w * 64 + lane) * NN + i0 + c * 8) = val;
  }
  if (t < 64) {
    e1[v * NN + i0 + t] = LOG2E * (ep1[0][t] + ep1[1][t] + ep1[2][t] + ep1[3][t]);
    e2[v * NN + i0 + t] = LOG2E * (ep2[0][t] + ep2[1][t] + ep2[2][t] + ep2[3][t]);
  }
}

// ---------------- e2 max per view ----------------
__global__ void e2max_kernel(const float* __restrict__ e2, float* __restrict__ e2m) {
  int v = blockIdx.x;
  __shared__ float red[256];
  float m = -1e30f;
  for (int i = threadIdx.x; i < NN; i += 256) m = fmaxf(m, e2[v * NN + i]);
  red[threadIdx.x] = m;
  __syncthreads();
  for (int s = 128; s > 0; s >>= 1) {
    if (threadIdx.x < s) red[threadIdx.x] = fmaxf(red[threadIdx.x], red[threadIdx.x + s]);
    __syncthreads();
  }
  if (threadIdx.x == 0) e2m[v] = red[0];
}

// ---------------- fused GAT aggregation: 32-row blocks, 3 blocks/CU ----------------
// grid (192, SPLIT, 3), 256 threads. Block: 32 rows x 256 d x 3072 j.
// acc = 32 regs -> fits 3 waves/EU (total budget 170). One barrier/tile,
// P double-buffered; B-frags direct from L2 (blocks sweep j in lockstep ->
// hT tile stays hot); adj prefetched one tile ahead post-barrier.
__global__ __launch_bounds__(256, 3) void gat_kernel(
    const int* __restrict__ adj0, const int* __restrict__ adj1, const int* __restrict__ adj2,
    const half_t* __restrict__ hT,
    const float* __restrict__ e1g, const float* __restrict__ e2g,
    const float* __restrict__ e2maxg, half_t* __restrict__ pacc, float* __restrict__ pl) {
  int v = blockIdx.z, s = blockIdx.y;
  const int* __restrict__ adjv = (v == 0) ? adj0 : (v == 1) ? adj1 : adj2;
  int i0 = blockIdx.x * 32;
  int t = threadIdx.x;
  int lane = t & 63, w = t >> 6;
  int lr = lane & 15, lg = lane >> 4;
  int jq = t & 15, rg = t >> 4;        // rg 0..15; rows il = it*16 + rg
  __shared__ half_t P0[32 * 64];       // 4 KB
  __shared__ half_t P1[32 * 64];       // 4 KB
  const half_t* hTv = hT + (size_t)v * DD * NN;
  const float* e2v = e2g + v * NN;
  const int jbase = s * JT * 64;

  float e1r[2], mr[2];
  float e2mL = e2maxg[v];
#pragma unroll
  for (int it = 0; it < 2; ++it) {
    float e1i = e1g[v * NN + i0 + it * 16 + rg];
    e1r[it] = e1i;
    float sm = e1i + e2mL;
    mr[it] = fmaxf(sm, 0.2f * sm);     // lrelu upper bound of row max (log2 units)
  }

  f32x4 acc[2][4] = {};
  float lpart[2] = {0.f, 0.f};
  f16x8 bC[2][4];
  int4 awA[2], awB[2];
  float4 e2A, e2B;

  auto load_b = [&](int jt) {
    int j0 = jbase + jt * 64;
#pragma unroll
    for (int kf = 0; kf < 2; ++kf)
#pragma unroll
      for (int nf = 0; nf < 4; ++nf)
        bC[kf][nf] = *(const f16x8*)(hTv + (size_t)(w * 64 + nf * 16 + lr) * NN +
                                     j0 + kf * 32 + lg * 8);
  };
  auto load_adj = [&](int4 (&aw)[2], int jt) {
    int j0 = jbase + jt * 64;
#pragma unroll
    for (int it = 0; it < 2; ++it)
      aw[it] = *(const int4*)(adjv + (size_t)(i0 + it * 16 + rg) * NN + j0 + jq * 4);
  };
  auto comp_p = [&](const int4 (&aw)[2], const float4& e2q, char* pb) {
    float e2a[4] = {e2q.x, e2q.y, e2q.z, e2q.w};
#pragma unroll
    for (int it = 0; it < 2; ++it) {
      int il = it * 16 + rg;
      int a4[4] = {aw[it].x, aw[it].y, aw[it].z, aw[it].w};
      f16x4 ph;
      float ssum = 0.f;
#pragma unroll
      for (int c = 0; c < 4; ++c) {
        float s1 = e1r[it] + e2a[c];
        float u = fmaxf(s1, 0.2f * s1) - mr[it];
        float p = (a4[c] > 0) ? exp2f(u) : 0.f;
        ssum += p;
        ph[c] = (half_t)p;
      }
      lpart[it] += ssum;
      unsigned addr = (unsigned)((il * 128 + jq * 8) ^ ((il & 7) << 4));
      *(f16x4*)(pb + addr) = ph;
    }
  };
  auto do_mfma = [&](const char* pb) {
#pragma unroll
    for (int kf = 0; kf < 2; ++kf)
#pragma unroll
      for (int mf = 0; mf < 2; ++mf) {
        int row = mf * 16 + lr;
        unsigned pa_ = (unsigned)((row * 128 + kf * 64 + lg * 16) ^ ((row & 7) << 4));
        f16x8 af = *(const f16x8*)(pb + pa_);
#pragma unroll
        for (int nf = 0; nf < 4; ++nf)
          acc[mf][nf] = mfma16(af, bC[kf][nf], acc[mf][nf]);
      }
  };

  // prologue
  load_adj(awA, 0);
  e2A = *(const float4*)(e2v + jbase + jq * 4);

  for (int tt = 0; tt < JT; tt += 2) {
    // tile tt: P0
    load_b(tt);
    comp_p(awA, e2A, (char*)P0);
    __syncthreads();                     // P0 visible (drains load_b too)
    if (tt + 1 < JT) {
      load_adj(awB, tt + 1);             // in flight across do_mfma
      e2B = *(const float4*)(e2v + jbase + (tt + 1) * 64 + jq * 4);
    }
    do_mfma((char*)P0);
    // tile tt+1: P1
    load_b(tt + 1);
    comp_p(awB, e2B, (char*)P1);
    __syncthreads();                     // P1 visible
    if (tt + 2 < JT) {
      load_adj(awA, tt + 2);
      e2A = *(const float4*)(e2v + jbase + (tt + 2) * 64 + jq * 4);
    }
    do_mfma((char*)P1);
  }

  // row sums: reduce over jq within 16-lane groups
  size_t sl = (size_t)v * SPLIT + s;
#pragma unroll
  for (int it = 0; it < 2; ++it) {
    float ssum = lpart[it];
    ssum += __shfl_xor(ssum, 1); ssum += __shfl_xor(ssum, 2);
    ssum += __shfl_xor(ssum, 4); ssum += __shfl_xor(ssum, 8);
    if (jq == 0) pl[sl * NN + i0 + it * 16 + rg] = ssum;
  }

  half_t* pa = pacc + sl * (size_t)NN * DD;
#pragma unroll
  for (int mf = 0; mf < 2; ++mf)
#pragma unroll
    for (int r = 0; r < 4; ++r) {
      int il = mf * 16 + lg * 4 + r;
#pragma unroll
      for (int nf = 0; nf < 4; ++nf)
        pa[(size_t)(i0 + il) * DD + w * 64 + nf * 16 + lr] = (half_t)acc[mf][nf][r];
    }
}

// ---------------- proj + LN + weighted combine (fused 2-slice combine) ----------------
__global__ __launch_bounds__(64) void proj_kernel(
    const half_t* __restrict__ pacc, const float* __restrict__ pl,
    const half_t* __restrict__ pWT,
    const float* __restrict__ proj_b, const float* __restrict__ ln_g,
    const float* __restrict__ ln_b, const float* __restrict__ alpha,
    float* __restrict__ out) {
  int i0 = blockIdx.x * 16;
  int t = threadIdx.x;
  int lr = t & 15, lg = t >> 4;
  float a0 = alpha[0], a1 = alpha[1], a2 = alpha[2];
  float am = fmaxf(a0, fmaxf(a1, a2));
  float x0 = __expf(a0 - am), x1 = __expf(a1 - am), x2 = __expf(a2 - am);
  float inv = 1.f / (x0 + x1 + x2);
  float wv[3] = {x0 * inv, x1 * inv, x2 * inv};
  __shared__ float rlv[3][16];
  if (t < 48) {
    int v = t >> 4, i = t & 15;
    float l = pl[((size_t)v * SPLIT + 0) * NN + i0 + i] +
              pl[((size_t)v * SPLIT + 1) * NN + i0 + i];
    rlv[v][i] = (l > 0.f) ? 1.f / l : 0.f;
  }
  float pb[8], gg[8], bb[8];
#pragma unroll
  for (int nf = 0; nf < 8; ++nf) {
    pb[nf] = proj_b[nf * 16 + lr];
    gg[nf] = ln_g[nf * 16 + lr];
    bb[nf] = ln_b[nf * 16 + lr];
  }
  __syncthreads();
  f32x4 zacc[8] = {};
  for (int v = 0; v < 3; ++v) {
    float rl = rlv[v][lr];
    f32x4 yac[8] = {};
    const half_t* p0 = pacc + (((size_t)v * SPLIT + 0) * NN + i0 + lr) * DD;
    const half_t* p1 = pacc + (((size_t)v * SPLIT + 1) * NN + i0 + lr) * DD;
    for (int kt = 0; kt < 8; ++kt) {
      int k = kt * 32 + lg * 8;
      f16x8 s0 = *(const f16x8*)(p0 + k);
      f16x8 s1 = *(const f16x8*)(p1 + k);
      f16x8 af;
#pragma unroll
      for (int e = 0; e < 8; ++e)
        af[e] = (half_t)(((float)s0[e] + (float)s1[e]) * rl);
#pragma unroll
      for (int nf = 0; nf < 8; ++nf) {
        f16x8 bf = *(const f16x8*)(pWT + (size_t)(nf * 16 + lr) * DD + k);
        yac[nf] = mfma16(af, bf, yac[nf]);
      }
    }
#pragma unroll
    for (int r = 0; r < 4; ++r) {
      float ssum = 0.f, q = 0.f;
#pragma unroll
      for (int nf = 0; nf < 8; ++nf) {
        float y = yac[nf][r] + pb[nf];
        yac[nf][r] = y;
        ssum += y; q += y * y;
      }
      ssum += __shfl_xor(ssum, 1); ssum += __shfl_xor(ssum, 2);
      ssum += __shfl_xor(ssum, 4); ssum += __shfl_xor(ssum, 8);
      q += __shfl_xor(q, 1); q += __shfl_xor(q, 2);
      q += __shfl_xor(q, 4); q += __shfl_xor(q, 8);
      float mean = ssum * (1.f / 128.f);
      float var = q * (1.f / 128.f) - mean * mean;
      float rstd = rsqrtf(var + 1e-5f);
      float wvv = wv[v];
#pragma unroll
      for (int nf = 0; nf < 8; ++nf)
        zacc[nf][r] += wvv * (yac[nf][r] - mean) * rstd;
    }
  }
#pragma unroll
  for (int nf = 0; nf < 8; ++nf)
#pragma unroll
    for (int r = 0; r < 4; ++r) {
      int row = i0 + lg * 4 + r;
      float z = zacc[nf][r] * gg[nf] + bb[nf];
      if (!isfinite(z)) z = 0.f;
      out[(size_t)row * OUT_DIM + nf * 16 + lr] = z;
    }
  if (blockIdx.x == 0 && t < 3) out[(size_t)NN * OUT_DIM + t] = wv[t];
}

// ---------------- launch ----------------
extern "C" void kernel_launch(void* const* d_in, const int* in_sizes, int n_in,
                              void* d_out, int out_size, void* d_ws, size_t ws_size,
                              hipStream_t stream) {
  const float* x      = (const float*)d_in[0];
  const int*   adj_cf = (const int*)d_in[1];
  const int*   adj_or = (const int*)d_in[2];
  const int*   adj_pe = (const int*)d_in[3];
  const float* W_cf   = (const float*)d_in[4];
  const float* as_cf  = (const float*)d_in[5];
  const float* ad_cf  = (const float*)d_in[6];
  const float* W_or   = (const float*)d_in[7];
  const float* as_or  = (const float*)d_in[8];
  const float* ad_or  = (const float*)d_in[9];
  const float* W_pe   = (const float*)d_in[10];
  const float* as_pe  = (const float*)d_in[11];
  const float* ad_pe  = (const float*)d_in[12];
  const float* proj_W = (const float*)d_in[13];
  const float* proj_b = (const float*)d_in[14];
  const float* ln_g   = (const float*)d_in[15];
  const float* ln_b   = (const float*)d_in[16];
  const float* alpha  = (const float*)d_in[17];

  char* ws = (char*)d_ws;
  half_t* xh     = (half_t*)(ws + 0);         // 6291456
  half_t* WT     = (half_t*)(ws + 6291456);   // 786432
  half_t* pWT    = (half_t*)(ws + 7077888);   // 65536
  half_t* hT     = (half_t*)(ws + 7143424);   // 9437184
  float*  e1     = (float*)(ws + 16580608);   // 73728
  float*  e2     = (float*)(ws + 16654336);   // 73728
  float*  e2m    = (float*)(ws + 16728064);   // 64
  half_t* pacc   = (half_t*)(ws + 16728128);  // 3*2*6144*256*2 = 18874368
  float*  pl     = (float*)(ws + 35602496);   // 3*2*6144*4 = 147456 (end ~35.75 MB)

  cvt_x_kernel<<<3072, 256, 0, stream>>>(x, xh);
  cvt_w_kernel<<<dim3(512, 4), 256, 0, stream>>>(W_cf, W_or, W_pe, proj_W, WT, pWT);
  gemm1_kernel<<<dim3(96, 3), 256, 0, stream>>>(xh, WT, as_cf, as_or, as_pe,
                                                ad_cf, ad_or, ad_pe, hT, e1, e2);
  e2max_kernel<<<3, 256, 0, stream>>>(e2, e2m);
  gat_kernel<<<dim3(192, SPLIT, 3), 256, 0, stream>>>(adj_cf, adj_or, adj_pe, hT,
                                                      e1, e2, e2m, pacc, pl);
  proj_kernel<<<384, 64, 0, stream>>>(pacc, pl, pWT, proj_b, ln_g, ln_b, alpha,
                                      (float*)d_out);
}

// Round 14
// 241.817 us; speedup vs baseline: 2.1190x; 1.4328x over previous
//
#include <hip/hip_runtime.h>

typedef _Float16 half_t;
typedef _Float16 f16x8 __attribute__((ext_vector_type(8)));
typedef _Float16 f16x4 __attribute__((ext_vector_type(4)));
typedef float f32x4 __attribute__((ext_vector_type(4)));
typedef unsigned long long u64;

#define NN 6144
#define IN_DIM 512
#define DD 256
#define OUT_DIM 128
#define SPLIT 4
#define JT 24        // j-tiles of 64 per slice (1536/64)
#define LOG2E 1.44269504088896340736f

__device__ __forceinline__ f32x4 mfma16(f16x8 a, f16x8 b, f32x4 c) {
  return __builtin_amdgcn_mfma_f32_16x16x32_f16(a, b, c, 0, 0, 0);
}

// monotone float<->uint encoding for atomicMax on floats of any sign
__device__ __forceinline__ unsigned enc_f(float f) {
  unsigned b = __float_as_uint(f);
  return (b & 0x80000000u) ? ~b : (b | 0x80000000u);
}
__device__ __forceinline__ float dec_f(unsigned u) {
  return (u & 0x80000000u) ? __uint_as_float(u & 0x7fffffffu)
                           : __uint_as_float(~u);
}

// ---------------- fused convert: x (f32->f16) + weights (convert+transpose) ----------------
// blocks [0,3072): x ; blocks [3072, 5120): W_v / proj_W ; block 3072 inits e2mu.
__global__ void cvt_kernel(const float* __restrict__ x,
                           const float* __restrict__ W0, const float* __restrict__ W1,
                           const float* __restrict__ W2, const float* __restrict__ pW,
                           half_t* __restrict__ xh, half_t* __restrict__ WT,
                           half_t* __restrict__ pWT, unsigned* __restrict__ e2mu) {
  int bx = blockIdx.x, t = threadIdx.x;
  if (bx < 3072) {
    int idx = (bx * 256 + t) * 4;
    float4 v = *(const float4*)(x + idx);
    f16x4 h;
    h[0] = (half_t)v.x; h[1] = (half_t)v.y; h[2] = (half_t)v.z; h[3] = (half_t)v.w;
    *(f16x4*)(xh + idx) = h;
    return;
  }
  int idx2 = bx - 3072;
  if (idx2 == 0 && t < 3) e2mu[t] = 0x00800000u;   // enc(-FLT_MAX)
  int y = idx2 >> 9;
  int idx = ((idx2 & 511) << 8) + t;
  if (y < 3) {
    const float* W = (y == 0) ? W0 : (y == 1) ? W1 : W2;
    int k = idx >> 8, n = idx & 255;
    WT[(size_t)y * DD * IN_DIM + (size_t)n * IN_DIM + k] = (half_t)W[idx];
  } else if (idx < DD * OUT_DIM) {
    int k = idx >> 7, o = idx & 127;
    pWT[(size_t)o * DD + k] = (half_t)pW[idx];
  }
}

// ---------------- GEMM1 + fused e-scores + fused e2-max ----------------
__global__ __launch_bounds__(256, 2) void gemm1_kernel(
    const half_t* __restrict__ xh, const half_t* __restrict__ WT,
    const float* __restrict__ as0, const float* __restrict__ as1, const float* __restrict__ as2,
    const float* __restrict__ ad0, const float* __restrict__ ad1, const float* __restrict__ ad2,
    half_t* __restrict__ hT, float* __restrict__ e1, float* __restrict__ e2,
    unsigned* __restrict__ e2mu) {
  int v = blockIdx.y;
  int i0 = blockIdx.x * 64;
  int t = threadIdx.x;
  int lane = t & 63, w = t >> 6;
  int lr = lane & 15, lg = lane >> 4;
  const half_t* Wv = WT + (size_t)v * DD * IN_DIM;
  const float* asv = (v == 0) ? as0 : (v == 1) ? as1 : as2;
  const float* adv = (v == 0) ? ad0 : (v == 1) ? ad1 : ad2;
  f32x4 acc[4][4] = {};
  for (int kt = 0; kt < 16; ++kt) {
    int k = kt * 32 + lg * 8;
    f16x8 af[4], bf[4];
#pragma unroll
    for (int mf = 0; mf < 4; ++mf)
      af[mf] = *(const f16x8*)(xh + (size_t)(i0 + mf * 16 + lr) * IN_DIM + k);
#pragma unroll
    for (int nf = 0; nf < 4; ++nf)
      bf[nf] = *(const f16x8*)(Wv + (size_t)(w * 64 + nf * 16 + lr) * IN_DIM + k);
#pragma unroll
    for (int mf = 0; mf < 4; ++mf)
#pragma unroll
      for (int nf = 0; nf < 4; ++nf)
        acc[mf][nf] = mfma16(af[mf], bf[nf], acc[mf][nf]);
  }
  __shared__ half_t tr[4][64 * 64];
  __shared__ float ep1[4][64], ep2[4][64];
  char* trw = (char*)tr[w];
#pragma unroll
  for (int mf = 0; mf < 4; ++mf)
#pragma unroll
    for (int nf = 0; nf < 4; ++nf)
#pragma unroll
      for (int r = 0; r < 4; ++r) {
        int dl = nf * 16 + lr;
        int il = mf * 16 + lg * 4 + r;
        unsigned addr = (unsigned)((dl * 128 + il * 2) ^ ((dl & 7) << 4));
        *(half_t*)(trw + addr) = (half_t)acc[mf][nf][r];
      }
  float as_c[4], ad_c[4];
#pragma unroll
  for (int nf = 0; nf < 4; ++nf) {
    int col = w * 64 + nf * 16 + lr;
    as_c[nf] = asv[col];
    ad_c[nf] = adv[col];
  }
#pragma unroll
  for (int mf = 0; mf < 4; ++mf)
#pragma unroll
    for (int r = 0; r < 4; ++r) {
      float p1 = 0.f, p2 = 0.f;
#pragma unroll
      for (int nf = 0; nf < 4; ++nf) {
        p1 = fmaf(acc[mf][nf][r], as_c[nf], p1);
        p2 = fmaf(acc[mf][nf][r], ad_c[nf], p2);
      }
      p1 += __shfl_xor(p1, 1); p1 += __shfl_xor(p1, 2);
      p1 += __shfl_xor(p1, 4); p1 += __shfl_xor(p1, 8);
      p2 += __shfl_xor(p2, 1); p2 += __shfl_xor(p2, 2);
      p2 += __shfl_xor(p2, 4); p2 += __shfl_xor(p2, 8);
      if (lr == 0) {
        int il = mf * 16 + lg * 4 + r;
        ep1[w][il] = p1;
        ep2[w][il] = p2;
      }
    }
  __syncthreads();
  half_t* hTv = hT + (size_t)v * DD * NN;
#pragma unroll
  for (int c = 0; c < 8; ++c) {
    unsigned addr = (unsigned)((lane * 128 + c * 16) ^ ((lane & 7) << 4));
    f16x8 val = *(const f16x8*)(trw + addr);
    *(f16x8*)(hTv + (size_t)(w * 64 + lane) * NN + i0 + c * 8) = val;
  }
  if (t < 64) {
    float e1v = LOG2E * (ep1[0][t] + ep1[1][t] + ep1[2][t] + ep1[3][t]);
    float e2v = LOG2E * (ep2[0][t] + ep2[1][t] + ep2[2][t] + ep2[3][t]);
    e1[v * NN + i0 + t] = e1v;
    e2[v * NN + i0 + t] = e2v;
    // fused per-view e2 max (ordered-uint atomicMax)
    float m = e2v;
    m = fmaxf(m, __shfl_xor(m, 1));  m = fmaxf(m, __shfl_xor(m, 2));
    m = fmaxf(m, __shfl_xor(m, 4));  m = fmaxf(m, __shfl_xor(m, 8));
    m = fmaxf(m, __shfl_xor(m, 16)); m = fmaxf(m, __shfl_xor(m, 32));
    if (t == 0) atomicMax(e2mu + v, enc_f(m));
  }
}

// ---------------- fused GAT aggregation (r11 structure, verbatim) ----------------
// grid (96, SPLIT, 3), 4 waves, 2 blocks/CU. Per tile (64 rows x 64 j):
//   comp_p(t) -> __syncthreads (drains gload(t), syncs P) ->
//   issue {adj,e2,gload}(t+1) -> mfma(t).
__global__ __launch_bounds__(256, 2) void gat_kernel(
    const int* __restrict__ adj0, const int* __restrict__ adj1, const int* __restrict__ adj2,
    const half_t* __restrict__ hT,
    const float* __restrict__ e1g, const float* __restrict__ e2g,
    const unsigned* __restrict__ e2mu, half_t* __restrict__ pacc, float* __restrict__ pl) {
  int v = blockIdx.z, s = blockIdx.y;
  const int* __restrict__ adjv = (v == 0) ? adj0 : (v == 1) ? adj1 : adj2;
  int i0 = blockIdx.x * 64;
  int t = threadIdx.x;
  int lane = t & 63, w = t >> 6;
  int lr = lane & 15, lg = lane >> 4;
  int jq = t & 15, rg = t >> 4;

  __shared__ half_t hbuf0[DD * 64];   // 32 KB
  __shared__ half_t hbuf1[DD * 64];   // 32 KB
  __shared__ half_t P0[64 * 64];      // 8 KB
  __shared__ half_t P1[64 * 64];      // 8 KB

  const half_t* hTv = hT + (size_t)v * DD * NN;
  const float* e2v = e2g + v * NN;
  const int jbase = s * JT * 64;

  float e1r[4], mr[4];
  float e2mL = dec_f(e2mu[v]);
#pragma unroll
  for (int it = 0; it < 4; ++it) {
    float e1i = e1g[v * NN + i0 + it * 16 + rg];
    e1r[it] = e1i;
    float sm = e1i + e2mL;
    mr[it] = fmaxf(sm, 0.2f * sm);   // lrelu upper bound of row max (log2 units)
  }

  f32x4 acc[4][4] = {};
  float lpart[4] = {0.f, 0.f, 0.f, 0.f};

  int sub = lane >> 3;
  int c_src = (lane & 7) ^ sub;
  auto gload = [&](half_t* hb, int jt) {
    int j0 = jbase + jt * 64;
#pragma unroll
    for (int q = 0; q < 8; ++q) {
      const half_t* gp = hTv + (size_t)(w * 64 + q * 8 + sub) * NN + j0 + c_src * 8;
      half_t* lp = hb + (w * 8 + q) * 512;
      __builtin_amdgcn_global_load_lds(
          (const __attribute__((address_space(1))) int*)gp,
          (__attribute__((address_space(3))) int*)lp, 16, 0, 0);
    }
  };
  auto load_adj = [&](int4 (&aw)[4], int jt) {
    int j0 = jbase + jt * 64;
#pragma unroll
    for (int it = 0; it < 4; ++it)
      aw[it] = *(const int4*)(adjv + (size_t)(i0 + it * 16 + rg) * NN + j0 + jq * 4);
  };
  auto comp_p = [&](const int4 (&aw)[4], const float4& e2q, char* pb) {
    float e2a[4] = {e2q.x, e2q.y, e2q.z, e2q.w};
#pragma unroll
    for (int it = 0; it < 4; ++it) {
      int il = it * 16 + rg;
      int a4[4] = {aw[it].x, aw[it].y, aw[it].z, aw[it].w};
      f16x4 ph;
      float ssum = 0.f;
#pragma unroll
      for (int c = 0; c < 4; ++c) {
        float s1 = e1r[it] + e2a[c];
        float u = fmaxf(s1, 0.2f * s1) - mr[it];
        float p = (a4[c] > 0) ? exp2f(u) : 0.f;
        ssum += p;
        ph[c] = (half_t)p;
      }
      lpart[it] += ssum;
      unsigned addr = (unsigned)((il * 128 + jq * 8) ^ ((il & 7) << 4));
      *(f16x4*)(pb + addr) = ph;
    }
  };
  auto do_mfma = [&](const char* pb, const half_t* hb) {
    __builtin_amdgcn_s_setprio(1);
#pragma unroll
    for (int kf = 0; kf < 2; ++kf) {
      f16x8 bfr[4];
#pragma unroll
      for (int nf = 0; nf < 4; ++nf) {
        int d = w * 64 + nf * 16 + lr;
        unsigned ba = (unsigned)(d * 128 + ((kf * 64 + lg * 16) ^ ((lr & 7) << 4)));
        bfr[nf] = *(const f16x8*)((const char*)hb + ba);
      }
#pragma unroll
      for (int mf = 0; mf < 4; ++mf) {
        int row = mf * 16 + lr;
        unsigned pa_ = (unsigned)((row * 128 + kf * 64 + lg * 16) ^ ((row & 7) << 4));
        f16x8 af = *(const f16x8*)(pb + pa_);
#pragma unroll
        for (int nf = 0; nf < 4; ++nf)
          acc[mf][nf] = mfma16(af, bfr[nf], acc[mf][nf]);
      }
    }
    __builtin_amdgcn_s_setprio(0);
  };

  int4 awA[4], awB[4];
  float4 e2A, e2B;

  // prologue: tile 0 in flight, then full drain once
  load_adj(awA, 0);
  e2A = *(const float4*)(e2v + jbase + jq * 4);
  gload(hbuf0, 0);
  __syncthreads();

  for (int tt = 0; tt < JT; tt += 2) {
    // even region: tile tt (P0, hbuf0)
    comp_p(awA, e2A, (char*)P0);
    __syncthreads();                       // drains gload(tt); P0 visible
    {
      load_adj(awB, tt + 1);               // adj/e2 first, gload last:
      e2B = *(const float4*)(e2v + jbase + (tt + 1) * 64 + jq * 4);
      gload(hbuf1, tt + 1);                // stays in flight past comp_p's waits
    }
    do_mfma((char*)P0, hbuf0);

    // odd region: tile tt+1 (P1, hbuf1)
    comp_p(awB, e2B, (char*)P1);
    __syncthreads();                       // drains gload(tt+1); P1 visible
    if (tt + 2 < JT) {
      load_adj(awA, tt + 2);
      e2A = *(const float4*)(e2v + jbase + (tt + 2) * 64 + jq * 4);
      gload(hbuf0, tt + 2);
    }
    do_mfma((char*)P1, hbuf1);
  }

  // row sums: reduce over jq within each 16-lane group, write pl directly
  size_t sl = (size_t)v * SPLIT + s;
#pragma unroll
  for (int it = 0; it < 4; ++it) {
    float ssum = lpart[it];
    ssum += __shfl_xor(ssum, 1); ssum += __shfl_xor(ssum, 2);
    ssum += __shfl_xor(ssum, 4); ssum += __shfl_xor(ssum, 8);
    if (jq == 0) pl[sl * NN + i0 + it * 16 + rg] = ssum;
  }

  half_t* pa = pacc + sl * (size_t)NN * DD;
#pragma unroll
  for (int mf = 0; mf < 4; ++mf)
#pragma unroll
    for (int r = 0; r < 4; ++r) {
      int il = mf * 16 + lg * 4 + r;
#pragma unroll
      for (int nf = 0; nf < 4; ++nf)
        pa[(size_t)(i0 + il) * DD + w * 64 + nf * 16 + lr] = (half_t)acc[mf][nf][r];
    }
}

// ---------------- proj + LN + weighted combine (fused slice-combine) ----------------
__global__ __launch_bounds__(64) void proj_kernel(
    const half_t* __restrict__ pacc, const float* __restrict__ pl,
    const half_t* __restrict__ pWT,
    const float* __restrict__ proj_b, const float* __restrict__ ln_g,
    const float* __restrict__ ln_b, const float* __restrict__ alpha,
    float* __restrict__ out) {
  int i0 = blockIdx.x * 16;
  int t = threadIdx.x;
  int lr = t & 15, lg = t >> 4;
  float a0 = alpha[0], a1 = alpha[1], a2 = alpha[2];
  float am = fmaxf(a0, fmaxf(a1, a2));
  float x0 = __expf(a0 - am), x1 = __expf(a1 - am), x2 = __expf(a2 - am);
  float inv = 1.f / (x0 + x1 + x2);
  float wv[3] = {x0 * inv, x1 * inv, x2 * inv};
  __shared__ float rlv[3][16];
  if (t < 48) {
    int v = t >> 4, i = t & 15;
    float l = 0.f;
#pragma unroll
    for (int s = 0; s < SPLIT; ++s)
      l += pl[((size_t)v * SPLIT + s) * NN + i0 + i];
    rlv[v][i] = (l > 0.f) ? 1.f / l : 0.f;
  }
  float pb[8], gg[8], bb[8];
#pragma unroll
  for (int nf = 0; nf < 8; ++nf) {
    pb[nf] = proj_b[nf * 16 + lr];
    gg[nf] = ln_g[nf * 16 + lr];
    bb[nf] = ln_b[nf * 16 + lr];
  }
  __syncthreads();
  f32x4 zacc[8] = {};
  for (int v = 0; v < 3; ++v) {
    float rl = rlv[v][lr];
    f32x4 yac[8] = {};
    const half_t* p0 = pacc + (((size_t)v * SPLIT + 0) * NN + i0 + lr) * DD;
    const half_t* p1 = pacc + (((size_t)v * SPLIT + 1) * NN + i0 + lr) * DD;
    const half_t* p2 = pacc + (((size_t)v * SPLIT + 2) * NN + i0 + lr) * DD;
    const half_t* p3 = pacc + (((size_t)v * SPLIT + 3) * NN + i0 + lr) * DD;
    for (int kt = 0; kt < 8; ++kt) {
      int k = kt * 32 + lg * 8;
      f16x8 s0 = *(const f16x8*)(p0 + k);
      f16x8 s1 = *(const f16x8*)(p1 + k);
      f16x8 s2 = *(const f16x8*)(p2 + k);
      f16x8 s3 = *(const f16x8*)(p3 + k);
      f16x8 af;
#pragma unroll
      for (int e = 0; e < 8; ++e)
        af[e] = (half_t)((((float)s0[e] + (float)s1[e]) +
                          ((float)s2[e] + (float)s3[e])) * rl);
#pragma unroll
      for (int nf = 0; nf < 8; ++nf) {
        f16x8 bf = *(const f16x8*)(pWT + (size_t)(nf * 16 + lr) * DD + k);
        yac[nf] = mfma16(af, bf, yac[nf]);
      }
    }
#pragma unroll
    for (int r = 0; r < 4; ++r) {
      float ssum = 0.f, q = 0.f;
#pragma unroll
      for (int nf = 0; nf < 8; ++nf) {
        float y = yac[nf][r] + pb[nf];
        yac[nf][r] = y;
        ssum += y; q += y * y;
      }
      ssum += __shfl_xor(ssum, 1); ssum += __shfl_xor(ssum, 2);
      ssum += __shfl_xor(ssum, 4); ssum += __shfl_xor(ssum, 8);
      q += __shfl_xor(q, 1); q += __shfl_xor(q, 2);
      q += __shfl_xor(q, 4); q += __shfl_xor(q, 8);
      float mean = ssum * (1.f / 128.f);
      float var = q * (1.f / 128.f) - mean * mean;
      float rstd = rsqrtf(var + 1e-5f);
      float wvv = wv[v];
#pragma unroll
      for (int nf = 0; nf < 8; ++nf)
        zacc[nf][r] += wvv * (yac[nf][r] - mean) * rstd;
    }
  }
#pragma unroll
  for (int nf = 0; nf < 8; ++nf)
#pragma unroll
    for (int r = 0; r < 4; ++r) {
      int row = i0 + lg * 4 + r;
      float z = zacc[nf][r] * gg[nf] + bb[nf];
      if (!isfinite(z)) z = 0.f;
      out[(size_t)row * OUT_DIM + nf * 16 + lr] = z;
    }
  if (blockIdx.x == 0 && t < 3) out[(size_t)NN * OUT_DIM + t] = wv[t];
}

// ---------------- launch ----------------
extern "C" void kernel_launch(void* const* d_in, const int* in_sizes, int n_in,
                              void* d_out, int out_size, void* d_ws, size_t ws_size,
                              hipStream_t stream) {
  const float* x      = (const float*)d_in[0];
  const int*   adj_cf = (const int*)d_in[1];
  const int*   adj_or = (const int*)d_in[2];
  const int*   adj_pe = (const int*)d_in[3];
  const float* W_cf   = (const float*)d_in[4];
  const float* as_cf  = (const float*)d_in[5];
  const float* ad_cf  = (const float*)d_in[6];
  const float* W_or   = (const float*)d_in[7];
  const float* as_or  = (const float*)d_in[8];
  const float* ad_or  = (const float*)d_in[9];
  const float* W_pe   = (const float*)d_in[10];
  const float* as_pe  = (const float*)d_in[11];
  const float* ad_pe  = (const float*)d_in[12];
  const float* proj_W = (const float*)d_in[13];
  const float* proj_b = (const float*)d_in[14];
  const float* ln_g   = (const float*)d_in[15];
  const float* ln_b   = (const float*)d_in[16];
  const float* alpha  = (const float*)d_in[17];

  char* ws = (char*)d_ws;
  half_t*   xh     = (half_t*)(ws + 0);         // 6291456
  half_t*   WT     = (half_t*)(ws + 6291456);   // 786432
  half_t*   pWT    = (half_t*)(ws + 7077888);   // 65536
  half_t*   hT     = (half_t*)(ws + 7143424);   // 9437184
  float*    e1     = (float*)(ws + 16580608);   // 73728
  float*    e2     = (float*)(ws + 16654336);   // 73728
  unsigned* e2mu   = (unsigned*)(ws + 16728064); // 64
  half_t*   pacc   = (half_t*)(ws + 16728128);  // 3*4*6144*256*2 = 37748736
  float*    pl     = (float*)(ws + 54476864);   // 3*4*6144*4 = 294912

  cvt_kernel<<<5120, 256, 0, stream>>>(x, W_cf, W_or, W_pe, proj_W, xh, WT, pWT, e2mu);
  gemm1_kernel<<<dim3(96, 3), 256, 0, stream>>>(xh, WT, as_cf, as_or, as_pe,
                                                ad_cf, ad_or, ad_pe, hT, e1, e2, e2mu);
  gat_kernel<<<dim3(96, SPLIT, 3), 256, 0, stream>>>(adj_cf, adj_or, adj_pe, hT,
                                                     e1, e2, e2mu, pacc, pl);
  proj_kernel<<<384, 64, 0, stream>>>(pacc, pl, pWT, proj_b, ln_g, ln_b, alpha,
                                      (float*)d_out);
}

// Round 15
// 238.452 us; speedup vs baseline: 2.1489x; 1.0141x over previous
//
#include <hip/hip_runtime.h>

typedef _Float16 half_t;
typedef _Float16 f16x8 __attribute__((ext_vector_type(8)));
typedef _Float16 f16x4 __attribute__((ext_vector_type(4)));
typedef float f32x4 __attribute__((ext_vector_type(4)));
typedef unsigned long long u64;

#define NN 6144
#define IN_DIM 512
#define DD 256
#define OUT_DIM 128
#define SPLIT 4
#define JT 24        // j-tiles of 64 per slice (1536/64)
#define LOG2E 1.44269504088896340736f

__device__ __forceinline__ f32x4 mfma16(f16x8 a, f16x8 b, f32x4 c) {
  return __builtin_amdgcn_mfma_f32_16x16x32_f16(a, b, c, 0, 0, 0);
}

// LDS-drain barrier (P visibility across waves); vmcnt NOT drained.
#define LBAR() asm volatile("s_waitcnt lgkmcnt(0)\n\ts_barrier" ::: "memory")
// counted vmem wait (no memory clobber; order pinned by sched_barrier)
#define VWAIT(N) asm volatile("s_waitcnt vmcnt(" #N ")")
#define SBAR() __builtin_amdgcn_sched_barrier(0)

// monotone float<->uint encoding for atomicMax on floats of any sign
__device__ __forceinline__ unsigned enc_f(float f) {
  unsigned b = __float_as_uint(f);
  return (b & 0x80000000u) ? ~b : (b | 0x80000000u);
}
__device__ __forceinline__ float dec_f(unsigned u) {
  return (u & 0x80000000u) ? __uint_as_float(u & 0x7fffffffu)
                           : __uint_as_float(~u);
}

// ---------------- fused convert: x (f32->f16) + weights (convert+transpose) ----------------
__global__ void cvt_kernel(const float* __restrict__ x,
                           const float* __restrict__ W0, const float* __restrict__ W1,
                           const float* __restrict__ W2, const float* __restrict__ pW,
                           half_t* __restrict__ xh, half_t* __restrict__ WT,
                           half_t* __restrict__ pWT, unsigned* __restrict__ e2mu) {
  int bx = blockIdx.x, t = threadIdx.x;
  if (bx < 3072) {
    int idx = (bx * 256 + t) * 4;
    float4 v = *(const float4*)(x + idx);
    f16x4 h;
    h[0] = (half_t)v.x; h[1] = (half_t)v.y; h[2] = (half_t)v.z; h[3] = (half_t)v.w;
    *(f16x4*)(xh + idx) = h;
    return;
  }
  int idx2 = bx - 3072;
  if (idx2 == 0 && t < 3) e2mu[t] = 0x00800000u;   // enc(-FLT_MAX)
  int y = idx2 >> 9;
  int idx = ((idx2 & 511) << 8) + t;
  if (y < 3) {
    const float* W = (y == 0) ? W0 : (y == 1) ? W1 : W2;
    int k = idx >> 8, n = idx & 255;
    WT[(size_t)y * DD * IN_DIM + (size_t)n * IN_DIM + k] = (half_t)W[idx];
  } else if (idx < DD * OUT_DIM) {
    int k = idx >> 7, o = idx & 127;
    pWT[(size_t)o * DD + k] = (half_t)pW[idx];
  }
}

// ---------------- GEMM1 + fused e-scores + fused e2-max ----------------
__global__ __launch_bounds__(256, 2) void gemm1_kernel(
    const half_t* __restrict__ xh, const half_t* __restrict__ WT,
    const float* __restrict__ as0, const float* __restrict__ as1, const float* __restrict__ as2,
    const float* __restrict__ ad0, const float* __restrict__ ad1, const float* __restrict__ ad2,
    half_t* __restrict__ hT, float* __restrict__ e1, float* __restrict__ e2,
    unsigned* __restrict__ e2mu) {
  int v = blockIdx.y;
  int i0 = blockIdx.x * 64;
  int t = threadIdx.x;
  int lane = t & 63, w = t >> 6;
  int lr = lane & 15, lg = lane >> 4;
  const half_t* Wv = WT + (size_t)v * DD * IN_DIM;
  const float* asv = (v == 0) ? as0 : (v == 1) ? as1 : as2;
  const float* adv = (v == 0) ? ad0 : (v == 1) ? ad1 : ad2;
  f32x4 acc[4][4] = {};
  for (int kt = 0; kt < 16; ++kt) {
    int k = kt * 32 + lg * 8;
    f16x8 af[4], bf[4];
#pragma unroll
    for (int mf = 0; mf < 4; ++mf)
      af[mf] = *(const f16x8*)(xh + (size_t)(i0 + mf * 16 + lr) * IN_DIM + k);
#pragma unroll
    for (int nf = 0; nf < 4; ++nf)
      bf[nf] = *(const f16x8*)(Wv + (size_t)(w * 64 + nf * 16 + lr) * IN_DIM + k);
#pragma unroll
    for (int mf = 0; mf < 4; ++mf)
#pragma unroll
      for (int nf = 0; nf < 4; ++nf)
        acc[mf][nf] = mfma16(af[mf], bf[nf], acc[mf][nf]);
  }
  __shared__ half_t tr[4][64 * 64];
  __shared__ float ep1[4][64], ep2[4][64];
  char* trw = (char*)tr[w];
#pragma unroll
  for (int mf = 0; mf < 4; ++mf)
#pragma unroll
    for (int nf = 0; nf < 4; ++nf)
#pragma unroll
      for (int r = 0; r < 4; ++r) {
        int dl = nf * 16 + lr;
        int il = mf * 16 + lg * 4 + r;
        unsigned addr = (unsigned)((dl * 128 + il * 2) ^ ((dl & 7) << 4));
        *(half_t*)(trw + addr) = (half_t)acc[mf][nf][r];
      }
  float as_c[4], ad_c[4];
#pragma unroll
  for (int nf = 0; nf < 4; ++nf) {
    int col = w * 64 + nf * 16 + lr;
    as_c[nf] = asv[col];
    ad_c[nf] = adv[col];
  }
#pragma unroll
  for (int mf = 0; mf < 4; ++mf)
#pragma unroll
    for (int r = 0; r < 4; ++r) {
      float p1 = 0.f, p2 = 0.f;
#pragma unroll
      for (int nf = 0; nf < 4; ++nf) {
        p1 = fmaf(acc[mf][nf][r], as_c[nf], p1);
        p2 = fmaf(acc[mf][nf][r], ad_c[nf], p2);
      }
      p1 += __shfl_xor(p1, 1); p1 += __shfl_xor(p1, 2);
      p1 += __shfl_xor(p1, 4); p1 += __shfl_xor(p1, 8);
      p2 += __shfl_xor(p2, 1); p2 += __shfl_xor(p2, 2);
      p2 += __shfl_xor(p2, 4); p2 += __shfl_xor(p2, 8);
      if (lr == 0) {
        int il = mf * 16 + lg * 4 + r;
        ep1[w][il] = p1;
        ep2[w][il] = p2;
      }
    }
  __syncthreads();
  half_t* hTv = hT + (size_t)v * DD * NN;
#pragma unroll
  for (int c = 0; c < 8; ++c) {
    unsigned addr = (unsigned)((lane * 128 + c * 16) ^ ((lane & 7) << 4));
    f16x8 val = *(const f16x8*)(trw + addr);
    *(f16x8*)(hTv + (size_t)(w * 64 + lane) * NN + i0 + c * 8) = val;
  }
  if (t < 64) {
    float e1v = LOG2E * (ep1[0][t] + ep1[1][t] + ep1[2][t] + ep1[3][t]);
    float e2v = LOG2E * (ep2[0][t] + ep2[1][t] + ep2[2][t] + ep2[3][t]);
    e1[v * NN + i0 + t] = e1v;
    e2[v * NN + i0 + t] = e2v;
    float m = e2v;
    m = fmaxf(m, __shfl_xor(m, 1));  m = fmaxf(m, __shfl_xor(m, 2));
    m = fmaxf(m, __shfl_xor(m, 4));  m = fmaxf(m, __shfl_xor(m, 8));
    m = fmaxf(m, __shfl_xor(m, 16)); m = fmaxf(m, __shfl_xor(m, 32));
    if (t == 0) atomicMax(e2mu + v, enc_f(m));
  }
}

// ---------------- fused GAT aggregation: counted-vmcnt pipeline (T4) ----------------
// grid (96, SPLIT, 3), 4 waves, 2 blocks/CU. Per region t:
//   comp_p(t) -> lgkmcnt(0)+s_barrier (P visible; vmem stays in flight)
//   -> VWAIT(5): drains exactly gload(t) [outstanding = 8 gload + 4 adj + 1 e2]
//   -> issue gload(t+1), then refill consumed adj-buf with adj(t+2) (depth 2)
//   -> mfma(t).
__global__ __launch_bounds__(256, 2) void gat_kernel(
    const int* __restrict__ adj0, const int* __restrict__ adj1, const int* __restrict__ adj2,
    const half_t* __restrict__ hT,
    const float* __restrict__ e1g, const float* __restrict__ e2g,
    const unsigned* __restrict__ e2mu, half_t* __restrict__ pacc, float* __restrict__ pl) {
  int v = blockIdx.z, s = blockIdx.y;
  const int* __restrict__ adjv = (v == 0) ? adj0 : (v == 1) ? adj1 : adj2;
  int i0 = blockIdx.x * 64;
  int t = threadIdx.x;
  int lane = t & 63, w = t >> 6;
  int lr = lane & 15, lg = lane >> 4;
  int jq = t & 15, rg = t >> 4;

  __shared__ half_t hbuf0[DD * 64];   // 32 KB
  __shared__ half_t hbuf1[DD * 64];   // 32 KB
  __shared__ half_t P0[64 * 64];      // 8 KB
  __shared__ half_t P1[64 * 64];      // 8 KB

  const half_t* hTv = hT + (size_t)v * DD * NN;
  const float* e2v = e2g + v * NN;
  const int jbase = s * JT * 64;

  float e1r[4], mr[4];
  float e2mL = dec_f(e2mu[v]);
#pragma unroll
  for (int it = 0; it < 4; ++it) {
    float e1i = e1g[v * NN + i0 + it * 16 + rg];
    e1r[it] = e1i;
    float sm = e1i + e2mL;
    mr[it] = fmaxf(sm, 0.2f * sm);   // lrelu upper bound of row max (log2 units)
  }

  f32x4 acc[4][4] = {};
  float lpart[4] = {0.f, 0.f, 0.f, 0.f};

  int sub = lane >> 3;
  int c_src = (lane & 7) ^ sub;
  auto gload = [&](half_t* hb, int jt) {
    int j0 = jbase + jt * 64;
#pragma unroll
    for (int q = 0; q < 8; ++q) {
      const half_t* gp = hTv + (size_t)(w * 64 + q * 8 + sub) * NN + j0 + c_src * 8;
      half_t* lp = hb + (w * 8 + q) * 512;
      __builtin_amdgcn_global_load_lds(
          (const __attribute__((address_space(1))) int*)gp,
          (__attribute__((address_space(3))) int*)lp, 16, 0, 0);
    }
  };
  auto load_adj = [&](int4 (&aw)[4], int jt) {
    int j0 = jbase + jt * 64;
#pragma unroll
    for (int it = 0; it < 4; ++it)
      aw[it] = *(const int4*)(adjv + (size_t)(i0 + it * 16 + rg) * NN + j0 + jq * 4);
  };
  auto comp_p = [&](const int4 (&aw)[4], const float4& e2q, char* pb) {
    float e2a[4] = {e2q.x, e2q.y, e2q.z, e2q.w};
#pragma unroll
    for (int it = 0; it < 4; ++it) {
      int il = it * 16 + rg;
      int a4[4] = {aw[it].x, aw[it].y, aw[it].z, aw[it].w};
      f16x4 ph;
      float ssum = 0.f;
#pragma unroll
      for (int c = 0; c < 4; ++c) {
        float s1 = e1r[it] + e2a[c];
        float u = fmaxf(s1, 0.2f * s1) - mr[it];
        float p = (a4[c] > 0) ? exp2f(u) : 0.f;
        ssum += p;
        ph[c] = (half_t)p;
      }
      lpart[it] += ssum;
      unsigned addr = (unsigned)((il * 128 + jq * 8) ^ ((il & 7) << 4));
      *(f16x4*)(pb + addr) = ph;
    }
  };
  auto do_mfma = [&](const char* pb, const half_t* hb) {
    __builtin_amdgcn_s_setprio(1);
#pragma unroll
    for (int kf = 0; kf < 2; ++kf) {
      f16x8 bfr[4];
#pragma unroll
      for (int nf = 0; nf < 4; ++nf) {
        int d = w * 64 + nf * 16 + lr;
        unsigned ba = (unsigned)(d * 128 + ((kf * 64 + lg * 16) ^ ((lr & 7) << 4)));
        bfr[nf] = *(const f16x8*)((const char*)hb + ba);
      }
#pragma unroll
      for (int mf = 0; mf < 4; ++mf) {
        int row = mf * 16 + lr;
        unsigned pa_ = (unsigned)((row * 128 + kf * 64 + lg * 16) ^ ((row & 7) << 4));
        f16x8 af = *(const f16x8*)(pb + pa_);
#pragma unroll
        for (int nf = 0; nf < 4; ++nf)
          acc[mf][nf] = mfma16(af, bfr[nf], acc[mf][nf]);
      }
    }
    __builtin_amdgcn_s_setprio(0);
  };

  int4 awA[4], awB[4];
  float4 e2A, e2B;

  // prologue: adj(0)/e2(0) FIRST (oldest), then gload(0), then adj(1)/e2(1).
  // comp_p(0)'s implicit wait for adj(0) does NOT drain gload(0) (in-order).
  load_adj(awA, 0);
  e2A = *(const float4*)(e2v + jbase + jq * 4);
  SBAR();
  gload(hbuf0, 0);
  SBAR();
  load_adj(awB, 1);
  e2B = *(const float4*)(e2v + jbase + 64 + jq * 4);
  SBAR();

  // full region: consume tile T (adj in AWc, P in Pc, hT in Hc);
  // refill AWc/E2c with tile T+2; stage hT(T+1) into Hn.
#define REGION_F(T, AWc, E2c, Pc, Hc, Hn)                            \
  {                                                                  \
    comp_p(AWc, E2c, (char*)(Pc));                                   \
    LBAR();                                                          \
    SBAR();                                                          \
    VWAIT(5);                                                        \
    SBAR();                                                          \
    gload(Hn, (T) + 1);                                              \
    SBAR();                                                          \
    load_adj(AWc, (T) + 2);                                          \
    E2c = *(const float4*)(e2v + jbase + ((T) + 2) * 64 + jq * 4);   \
    SBAR();                                                          \
    do_mfma((char*)(Pc), Hc);                                        \
  }

  for (int tt = 0; tt < JT - 2; tt += 2) {
    REGION_F(tt,     awA, e2A, P0, hbuf0, hbuf1);
    REGION_F(tt + 1, awB, e2B, P1, hbuf1, hbuf0);
  }
  // region JT-2: stage gload(JT-1); no adj refill. outstanding at wait = 13.
  {
    comp_p(awA, e2A, (char*)P0);
    LBAR();
    SBAR();
    VWAIT(5);
    SBAR();
    gload(hbuf1, JT - 1);
    SBAR();
    do_mfma((char*)P0, hbuf0);
  }
  // region JT-1: outstanding at wait = 8 (gload only) -> drain fully.
  {
    comp_p(awB, e2B, (char*)P1);
    LBAR();
    SBAR();
    VWAIT(0);
    SBAR();
    do_mfma((char*)P1, hbuf1);
  }
#undef REGION_F

  // row sums: reduce over jq within each 16-lane group, write pl directly
  size_t sl = (size_t)v * SPLIT + s;
#pragma unroll
  for (int it = 0; it < 4; ++it) {
    float ssum = lpart[it];
    ssum += __shfl_xor(ssum, 1); ssum += __shfl_xor(ssum, 2);
    ssum += __shfl_xor(ssum, 4); ssum += __shfl_xor(ssum, 8);
    if (jq == 0) pl[sl * NN + i0 + it * 16 + rg] = ssum;
  }

  half_t* pa = pacc + sl * (size_t)NN * DD;
#pragma unroll
  for (int mf = 0; mf < 4; ++mf)
#pragma unroll
    for (int r = 0; r < 4; ++r) {
      int il = mf * 16 + lg * 4 + r;
#pragma unroll
      for (int nf = 0; nf < 4; ++nf)
        pa[(size_t)(i0 + il) * DD + w * 64 + nf * 16 + lr] = (half_t)acc[mf][nf][r];
    }
}

// ---------------- proj + LN + weighted combine (fused slice-combine) ----------------
__global__ __launch_bounds__(64) void proj_kernel(
    const half_t* __restrict__ pacc, const float* __restrict__ pl,
    const half_t* __restrict__ pWT,
    const float* __restrict__ proj_b, const float* __restrict__ ln_g,
    const float* __restrict__ ln_b, const float* __restrict__ alpha,
    float* __restrict__ out) {
  int i0 = blockIdx.x * 16;
  int t = threadIdx.x;
  int lr = t & 15, lg = t >> 4;
  float a0 = alpha[0], a1 = alpha[1], a2 = alpha[2];
  float am = fmaxf(a0, fmaxf(a1, a2));
  float x0 = __expf(a0 - am), x1 = __expf(a1 - am), x2 = __expf(a2 - am);
  float inv = 1.f / (x0 + x1 + x2);
  float wv[3] = {x0 * inv, x1 * inv, x2 * inv};
  __shared__ float rlv[3][16];
  if (t < 48) {
    int v = t >> 4, i = t & 15;
    float l = 0.f;
#pragma unroll
    for (int s = 0; s < SPLIT; ++s)
      l += pl[((size_t)v * SPLIT + s) * NN + i0 + i];
    rlv[v][i] = (l > 0.f) ? 1.f / l : 0.f;
  }
  float pb[8], gg[8], bb[8];
#pragma unroll
  for (int nf = 0; nf < 8; ++nf) {
    pb[nf] = proj_b[nf * 16 + lr];
    gg[nf] = ln_g[nf * 16 + lr];
    bb[nf] = ln_b[nf * 16 + lr];
  }
  __syncthreads();
  f32x4 zacc[8] = {};
  for (int v = 0; v < 3; ++v) {
    float rl = rlv[v][lr];
    f32x4 yac[8] = {};
    const half_t* p0 = pacc + (((size_t)v * SPLIT + 0) * NN + i0 + lr) * DD;
    const half_t* p1 = pacc + (((size_t)v * SPLIT + 1) * NN + i0 + lr) * DD;
    const half_t* p2 = pacc + (((size_t)v * SPLIT + 2) * NN + i0 + lr) * DD;
    const half_t* p3 = pacc + (((size_t)v * SPLIT + 3) * NN + i0 + lr) * DD;
    for (int kt = 0; kt < 8; ++kt) {
      int k = kt * 32 + lg * 8;
      f16x8 s0 = *(const f16x8*)(p0 + k);
      f16x8 s1 = *(const f16x8*)(p1 + k);
      f16x8 s2 = *(const f16x8*)(p2 + k);
      f16x8 s3 = *(const f16x8*)(p3 + k);
      f16x8 af;
#pragma unroll
      for (int e = 0; e < 8; ++e)
        af[e] = (half_t)((((float)s0[e] + (float)s1[e]) +
                          ((float)s2[e] + (float)s3[e])) * rl);
#pragma unroll
      for (int nf = 0; nf < 8; ++nf) {
        f16x8 bf = *(const f16x8*)(pWT + (size_t)(nf * 16 + lr) * DD + k);
        yac[nf] = mfma16(af, bf, yac[nf]);
      }
    }
#pragma unroll
    for (int r = 0; r < 4; ++r) {
      float ssum = 0.f, q = 0.f;
#pragma unroll
      for (int nf = 0; nf < 8; ++nf) {
        float y = yac[nf][r] + pb[nf];
        yac[nf][r] = y;
        ssum += y; q += y * y;
      }
      ssum += __shfl_xor(ssum, 1); ssum += __shfl_xor(ssum, 2);
      ssum += __shfl_xor(ssum, 4); ssum += __shfl_xor(ssum, 8);
      q += __shfl_xor(q, 1); q += __shfl_xor(q, 2);
      q += __shfl_xor(q, 4); q += __shfl_xor(q, 8);
      float mean = ssum * (1.f / 128.f);
      float var = q * (1.f / 128.f) - mean * mean;
      float rstd = rsqrtf(var + 1e-5f);
      float wvv = wv[v];
#pragma unroll
      for (int nf = 0; nf < 8; ++nf)
        zacc[nf][r] += wvv * (yac[nf][r] - mean) * rstd;
    }
  }
#pragma unroll
  for (int nf = 0; nf < 8; ++nf)
#pragma unroll
    for (int r = 0; r < 4; ++r) {
      int row = i0 + lg * 4 + r;
      float z = zacc[nf][r] * gg[nf] + bb[nf];
      if (!isfinite(z)) z = 0.f;
      out[(size_t)row * OUT_DIM + nf * 16 + lr] = z;
    }
  if (blockIdx.x == 0 && t < 3) out[(size_t)NN * OUT_DIM + t] = wv[t];
}

// ---------------- launch ----------------
extern "C" void kernel_launch(void* const* d_in, const int* in_sizes, int n_in,
                              void* d_out, int out_size, void* d_ws, size_t ws_size,
                              hipStream_t stream) {
  const float* x      = (const float*)d_in[0];
  const int*   adj_cf = (const int*)d_in[1];
  const int*   adj_or = (const int*)d_in[2];
  const int*   adj_pe = (const int*)d_in[3];
  const float* W_cf   = (const float*)d_in[4];
  const float* as_cf  = (const float*)d_in[5];
  const float* ad_cf  = (const float*)d_in[6];
  const float* W_or   = (const float*)d_in[7];
  const float* as_or  = (const float*)d_in[8];
  const float* ad_or  = (const float*)d_in[9];
  const float* W_pe   = (const float*)d_in[10];
  const float* as_pe  = (const float*)d_in[11];
  const float* ad_pe  = (const float*)d_in[12];
  const float* proj_W = (const float*)d_in[13];
  const float* proj_b = (const float*)d_in[14];
  const float* ln_g   = (const float*)d_in[15];
  const float* ln_b   = (const float*)d_in[16];
  const float* alpha  = (const float*)d_in[17];

  char* ws = (char*)d_ws;
  half_t*   xh     = (half_t*)(ws + 0);         // 6291456
  half_t*   WT     = (half_t*)(ws + 6291456);   // 786432
  half_t*   pWT    = (half_t*)(ws + 7077888);   // 65536
  half_t*   hT     = (half_t*)(ws + 7143424);   // 9437184
  float*    e1     = (float*)(ws + 16580608);   // 73728
  float*    e2     = (float*)(ws + 16654336);   // 73728
  unsigned* e2mu   = (unsigned*)(ws + 16728064); // 64
  half_t*   pacc   = (half_t*)(ws + 16728128);  // 37748736
  float*    pl     = (float*)(ws + 54476864);   // 294912

  cvt_kernel<<<5120, 256, 0, stream>>>(x, W_cf, W_or, W_pe, proj_W, xh, WT, pWT, e2mu);
  gemm1_kernel<<<dim3(96, 3), 256, 0, stream>>>(xh, WT, as_cf, as_or, as_pe,
                                                ad_cf, ad_or, ad_pe, hT, e1, e2, e2mu);
  gat_kernel<<<dim3(96, SPLIT, 3), 256, 0, stream>>>(adj_cf, adj_or, adj_pe, hT,
                                                     e1, e2, e2mu, pacc, pl);
  proj_kernel<<<384, 64, 0, stream>>>(pacc, pl, pWT, proj_b, ln_g, ln_b, alpha,
                                      (float*)d_out);
}